// Round 1
// baseline (793.997 us; speedup 1.0000x reference)
//
#include <hip/hip_runtime.h>
#include <cmath>

typedef unsigned short ushort_t;
typedef __attribute__((ext_vector_type(8))) short short8;
typedef __attribute__((ext_vector_type(4))) float f32x4;

#define D_IN   4096
#define D_OUT  4096
#define T_TOK  8192
#define E_EXP  8
#define R_RANK 16
#define KCAT   4224   // 4096 + E*R
#define SCALE_LORA 2.0f

__device__ __forceinline__ ushort_t f2bf(float f) {
    unsigned int u = __float_as_uint(f);
    u += 0x7fffu + ((u >> 16) & 1u);   // RNE
    return (ushort_t)(u >> 16);
}

// ---------------------------------------------------------------------------
// K1: Wcat[o][0:4096]=bf16(Wb[o]); Wcat[o][4096+e*16+r]=bf16(Bm[e][o][r]);
//     Abf[e*16+r][:] = bf16(A[e][r][:])
// ---------------------------------------------------------------------------
__global__ __launch_bounds__(256) void build_weights(
    const float* __restrict__ Wb, const float* __restrict__ Bm,
    const float* __restrict__ A, ushort_t* __restrict__ Wcat,
    ushort_t* __restrict__ Abf) {
    int b = blockIdx.x;
    int tid = threadIdx.x;
    if (b < D_OUT) {
        const float4* src = (const float4*)(Wb + (size_t)b * D_IN);
        ushort_t* drow = Wcat + (size_t)b * KCAT;
        for (int c4 = tid; c4 < D_IN / 4; c4 += 256) {
            float4 v = src[c4];
            ushort4 o;
            o.x = f2bf(v.x); o.y = f2bf(v.y); o.z = f2bf(v.z); o.w = f2bf(v.w);
            ((ushort4*)drow)[c4] = o;
        }
        if (tid < E_EXP * R_RANK) {
            int e = tid >> 4, r = tid & 15;
            drow[D_IN + tid] = f2bf(Bm[((size_t)e * D_OUT + b) * R_RANK + r]);
        }
    } else {
        int er = b - D_OUT;   // 0..127
        const float4* src = (const float4*)(A + (size_t)er * D_IN);
        ushort_t* drow = Abf + (size_t)er * D_IN;
        for (int c4 = tid; c4 < D_IN / 4; c4 += 256) {
            float4 v = src[c4];
            ushort4 o;
            o.x = f2bf(v.x); o.y = f2bf(v.y); o.z = f2bf(v.z); o.w = f2bf(v.w);
            ((ushort4*)drow)[c4] = o;
        }
    }
}

// ---------------------------------------------------------------------------
// K2: one wave per token. fp32 router logits (8 dots of 4096) + x->bf16 into
//     xcat cols 0..4095. Top-2 + renormalized weights written per token.
// ---------------------------------------------------------------------------
__global__ __launch_bounds__(256) void router_convert(
    const float* __restrict__ x, const float* __restrict__ Wr,
    ushort_t* __restrict__ xcat, int2* __restrict__ eids,
    float2* __restrict__ wts) {
    int lane = threadIdx.x & 63;
    int wave = threadIdx.x >> 6;
    int t = blockIdx.x * 4 + wave;
    const float4* xr = (const float4*)(x + (size_t)t * D_IN);
    ushort4* xo = (ushort4*)(xcat + (size_t)t * KCAT);
    float acc[E_EXP];
#pragma unroll
    for (int e = 0; e < E_EXP; e++) acc[e] = 0.f;
    for (int c4 = lane; c4 < D_IN / 4; c4 += 64) {
        float4 v = xr[c4];
        ushort4 o;
        o.x = f2bf(v.x); o.y = f2bf(v.y); o.z = f2bf(v.z); o.w = f2bf(v.w);
        xo[c4] = o;
#pragma unroll
        for (int e = 0; e < E_EXP; e++) {
            float4 wv = ((const float4*)(Wr + (size_t)e * D_IN))[c4];
            acc[e] += v.x * wv.x + v.y * wv.y + v.z * wv.z + v.w * wv.w;
        }
    }
#pragma unroll
    for (int e = 0; e < E_EXP; e++) {
#pragma unroll
        for (int off = 32; off > 0; off >>= 1)
            acc[e] += __shfl_xor(acc[e], off, 64);
    }
    if (lane == 0) {
        int e0 = 0; float l0 = acc[0];
#pragma unroll
        for (int e = 1; e < E_EXP; e++)
            if (acc[e] > l0) { l0 = acc[e]; e0 = e; }
        int e1 = -1; float l1 = -3.4e38f;
#pragma unroll
        for (int e = 0; e < E_EXP; e++)
            if (e != e0 && acc[e] > l1) { l1 = acc[e]; e1 = e; }
        // softmax + top2 + renorm == 1/(1+exp(l1-l0))
        float w0 = 1.f / (1.f + expf(l1 - l0));
        eids[t] = make_int2(e0, e1);
        wts[t] = make_float2(w0, 1.f - w0);
    }
}

// ---------------------------------------------------------------------------
// K4: v[t][c] = bf16( coef(c>>4) * h[t][c] ), coef = SCALE*w for top-2 else 0.
//     Written into xcat cols 4096..4223.
// ---------------------------------------------------------------------------
__global__ __launch_bounds__(256) void build_v(
    const float* __restrict__ h, const int2* __restrict__ eids,
    const float2* __restrict__ wts, ushort_t* __restrict__ xcat) {
    int t = blockIdx.x * 256 + threadIdx.x;
    int2 e = eids[t];
    float2 w = wts[t];
    const float* ht = h + (size_t)t * (E_EXP * R_RANK);
    uint4* dst = (uint4*)(xcat + (size_t)t * KCAT + D_IN);
    for (int q = 0; q < 16; q++) {
        __align__(16) ushort_t tmp[8];
#pragma unroll
        for (int j = 0; j < 8; j++) {
            int c = q * 8 + j;
            int ce = c >> 4;
            float coef = (ce == e.x) ? (SCALE_LORA * w.x)
                       : ((ce == e.y) ? (SCALE_LORA * w.y) : 0.f);
            tmp[j] = f2bf(coef * ht[c]);
        }
        dst[q] = *(const uint4*)tmp;
    }
}

// ---------------------------------------------------------------------------
// GEMM (B^T layout): C[m,n] = sum_k A[m,k]*B[n,k] (+bias[n]).
// 128x128 tile / block (4 waves, each 64x64 via 4x4 of 16x16x32 MFMA), BK=32,
// global_load_lds width-16 staging (m97 structure).
// ---------------------------------------------------------------------------
__global__ __launch_bounds__(256) void gemm_bt(
    const ushort_t* __restrict__ Am, const ushort_t* __restrict__ Bmat,
    float* __restrict__ C, const float* __restrict__ bias,
    int K, int lda, int ldb, int ldc) {
    __shared__ __align__(16) ushort_t lA[128 * 32];
    __shared__ __align__(16) ushort_t lB[128 * 32];
    int tid = threadIdx.x;
    int lane = tid & 63, wave = tid >> 6;
    const int rowBase = blockIdx.x * 128;
    const int colBase = blockIdx.y * 128;
    const ushort_t* gA = Am + (size_t)rowBase * lda;
    const ushort_t* gB = Bmat + (size_t)colBase * ldb;

    // staging: 512 chunks of 16B per tile; thread handles chunks tid, tid+256
    int c0 = tid, c1 = tid + 256;
    int r0 = c0 >> 2, k0 = (c0 & 3) * 8;
    int r1 = c1 >> 2, k1 = (c1 & 3) * 8;
    ushort_t* lA0 = lA + (size_t)wave * 512;          // wave-uniform LDS bases
    ushort_t* lA1 = lA + 2048 + (size_t)wave * 512;
    ushort_t* lB0 = lB + (size_t)wave * 512;
    ushort_t* lB1 = lB + 2048 + (size_t)wave * 512;

    f32x4 acc[4][4];
#pragma unroll
    for (int i = 0; i < 4; i++)
#pragma unroll
        for (int j = 0; j < 4; j++)
            acc[i][j] = (f32x4){0.f, 0.f, 0.f, 0.f};

    int m0 = (wave >> 1) * 64, n0 = (wave & 1) * 64;
    int row16 = lane & 15, q8 = (lane >> 4) * 8;

    for (int kt = 0; kt < K; kt += 32) {
        __syncthreads();
        __builtin_amdgcn_global_load_lds(
            (const __attribute__((address_space(1))) unsigned int*)(gA + (size_t)r0 * lda + kt + k0),
            (__attribute__((address_space(3))) unsigned int*)lA0, 16, 0, 0);
        __builtin_amdgcn_global_load_lds(
            (const __attribute__((address_space(1))) unsigned int*)(gA + (size_t)r1 * lda + kt + k1),
            (__attribute__((address_space(3))) unsigned int*)lA1, 16, 0, 0);
        __builtin_amdgcn_global_load_lds(
            (const __attribute__((address_space(1))) unsigned int*)(gB + (size_t)r0 * ldb + kt + k0),
            (__attribute__((address_space(3))) unsigned int*)lB0, 16, 0, 0);
        __builtin_amdgcn_global_load_lds(
            (const __attribute__((address_space(1))) unsigned int*)(gB + (size_t)r1 * ldb + kt + k1),
            (__attribute__((address_space(3))) unsigned int*)lB1, 16, 0, 0);
        __syncthreads();

        short8 af[4], bfr[4];
#pragma unroll
        for (int i = 0; i < 4; i++)
            af[i] = *(const short8*)&lA[(m0 + i * 16 + row16) * 32 + q8];
#pragma unroll
        for (int j = 0; j < 4; j++)
            bfr[j] = *(const short8*)&lB[(n0 + j * 16 + row16) * 32 + q8];
#pragma unroll
        for (int i = 0; i < 4; i++)
#pragma unroll
            for (int j = 0; j < 4; j++)
                acc[i][j] = __builtin_amdgcn_mfma_f32_16x16x32_bf16(
                    af[i], bfr[j], acc[i][j], 0, 0, 0);
    }

    // epilogue: C/D layout col=lane&15, row=(lane>>4)*4+reg
#pragma unroll
    for (int i = 0; i < 4; i++) {
        int r = rowBase + m0 + i * 16 + (lane >> 4) * 4;
#pragma unroll
        for (int j = 0; j < 4; j++) {
            int cidx = colBase + n0 + j * 16 + (lane & 15);
            float badd = bias ? bias[cidx] : 0.f;
#pragma unroll
            for (int reg = 0; reg < 4; reg++)
                C[(size_t)(r + reg) * ldc + cidx] = acc[i][j][reg] + badd;
        }
    }
}

// ---------------------------------------------------------------------------
extern "C" void kernel_launch(void* const* d_in, const int* in_sizes, int n_in,
                              void* d_out, int out_size, void* d_ws, size_t ws_size,
                              hipStream_t stream) {
    const float* x    = (const float*)d_in[0];   // [4,2048,4096]
    const float* Wb   = (const float*)d_in[1];   // [4096,4096]
    const float* bias = (const float*)d_in[2];   // [4096]
    const float* Wr   = (const float*)d_in[3];   // [8,4096]
    const float* A    = (const float*)d_in[4];   // [8,16,4096]
    const float* Bm   = (const float*)d_in[5];   // [8,4096,16]
    float* out = (float*)d_out;

    char* p = (char*)d_ws;
    ushort_t* xcat = (ushort_t*)p; p += (size_t)T_TOK * KCAT * 2;   // 69.2 MB
    ushort_t* Wcat = (ushort_t*)p; p += (size_t)D_OUT * KCAT * 2;   // 34.6 MB
    ushort_t* Abf  = (ushort_t*)p; p += (size_t)(E_EXP * R_RANK) * D_IN * 2; // 1 MB
    float*    h    = (float*)p;    p += (size_t)T_TOK * (E_EXP * R_RANK) * 4; // 4 MB
    int2*     eids = (int2*)p;     p += (size_t)T_TOK * sizeof(int2);
    float2*   wts  = (float2*)p;   p += (size_t)T_TOK * sizeof(float2);

    build_weights<<<D_OUT + E_EXP * R_RANK, 256, 0, stream>>>(Wb, Bm, A, Wcat, Abf);
    router_convert<<<T_TOK / 4, 256, 0, stream>>>(x, Wr, xcat, eids, wts);
    // h[8192,128] = xcat[:, :4096] @ Abf^T
    gemm_bt<<<dim3(T_TOK / 128, 1), 256, 0, stream>>>(
        xcat, Abf, h, nullptr, D_IN, KCAT, D_IN, E_EXP * R_RANK);
    build_v<<<T_TOK / 256, 256, 0, stream>>>(h, eids, wts, xcat);
    // out[8192,4096] = xcat @ Wcat^T + bias  (K = 4224 includes LoRA fold)
    gemm_bt<<<dim3(T_TOK / 128, D_OUT / 128), 256, 0, stream>>>(
        xcat, Wcat, out, bias, KCAT, KCAT, KCAT, D_OUT);
}

// Round 2
// 742.770 us; speedup vs baseline: 1.0690x; 1.0690x over previous
//
#include <hip/hip_runtime.h>
#include <cmath>

typedef unsigned short ushort_t;
typedef __attribute__((ext_vector_type(8))) short short8;
typedef __attribute__((ext_vector_type(4))) float f32x4;

#define D_IN   4096
#define D_OUT  4096
#define T_TOK  8192
#define E_EXP  8
#define R_RANK 16
#define KCAT   4224   // 4096 + E*R
#define SCALE_LORA 2.0f

__device__ __forceinline__ ushort_t f2bf(float f) {
    unsigned int u = __float_as_uint(f);
    u += 0x7fffu + ((u >> 16) & 1u);   // RNE
    return (ushort_t)(u >> 16);
}

// ---------------------------------------------------------------------------
// K1: Wcat[o][0:4096]=bf16(Wb[o]); Wcat[o][4096+e*16+r]=bf16(Bm[e][o][r]);
//     Abf[e*16+r][:] = bf16(A[e][r][:])
// ---------------------------------------------------------------------------
__global__ __launch_bounds__(256) void build_weights(
    const float* __restrict__ Wb, const float* __restrict__ Bm,
    const float* __restrict__ A, ushort_t* __restrict__ Wcat,
    ushort_t* __restrict__ Abf) {
    int b = blockIdx.x;
    int tid = threadIdx.x;
    if (b < D_OUT) {
        const float4* src = (const float4*)(Wb + (size_t)b * D_IN);
        ushort_t* drow = Wcat + (size_t)b * KCAT;
        for (int c4 = tid; c4 < D_IN / 4; c4 += 256) {
            float4 v = src[c4];
            ushort4 o;
            o.x = f2bf(v.x); o.y = f2bf(v.y); o.z = f2bf(v.z); o.w = f2bf(v.w);
            ((ushort4*)drow)[c4] = o;
        }
        if (tid < E_EXP * R_RANK) {
            int e = tid >> 4, r = tid & 15;
            drow[D_IN + tid] = f2bf(Bm[((size_t)e * D_OUT + b) * R_RANK + r]);
        }
    } else {
        int er = b - D_OUT;   // 0..127
        const float4* src = (const float4*)(A + (size_t)er * D_IN);
        ushort_t* drow = Abf + (size_t)er * D_IN;
        for (int c4 = tid; c4 < D_IN / 4; c4 += 256) {
            float4 v = src[c4];
            ushort4 o;
            o.x = f2bf(v.x); o.y = f2bf(v.y); o.z = f2bf(v.z); o.w = f2bf(v.w);
            ((ushort4*)drow)[c4] = o;
        }
    }
}

// ---------------------------------------------------------------------------
// K2: router + x->bf16 convert. Block = 4 tokens (4 waves). Wr staged in LDS
//     fp32 in 2 halves (4 experts = 64 KB); two passes over x (2nd is L1/L2
//     hit). Inner loop reads Wr from LDS (stride-1 b128, conflict-free),
//     killing the per-token 128 KB L1-miss re-read of the old version.
// ---------------------------------------------------------------------------
__global__ __launch_bounds__(256) void router_convert(
    const float* __restrict__ x, const float* __restrict__ Wr,
    ushort_t* __restrict__ xcat, int2* __restrict__ eids,
    float2* __restrict__ wts) {
    __shared__ float sWr[4 * D_IN];   // 64 KB: 4 experts fp32
    int tid = threadIdx.x;
    int lane = tid & 63;
    int wave = tid >> 6;
    int t = blockIdx.x * 4 + wave;
    const float4* xr = (const float4*)(x + (size_t)t * D_IN);
    ushort4* xo = (ushort4*)(xcat + (size_t)t * KCAT);

    float acc[E_EXP];
#pragma unroll
    for (int e = 0; e < E_EXP; e++) acc[e] = 0.f;

#pragma unroll
    for (int half = 0; half < 2; half++) {
        __syncthreads();
        // stage Wr[half*4 .. half*4+3][:] -> LDS (4096 float4s, 16/thread)
        {
            const float4* wsrc = (const float4*)(Wr + (size_t)half * 4 * D_IN);
            float4* wdst = (float4*)sWr;
#pragma unroll
            for (int q = 0; q < 16; q++)
                wdst[tid + q * 256] = wsrc[tid + q * 256];
        }
        __syncthreads();

        for (int c4 = lane; c4 < D_IN / 4; c4 += 64) {
            float4 v = xr[c4];
            if (half == 0) {
                ushort4 o;
                o.x = f2bf(v.x); o.y = f2bf(v.y); o.z = f2bf(v.z); o.w = f2bf(v.w);
                xo[c4] = o;
            }
#pragma unroll
            for (int e4 = 0; e4 < 4; e4++) {
                float4 wv = ((const float4*)(sWr + (size_t)e4 * D_IN))[c4];
                acc[half * 4 + e4] += v.x * wv.x + v.y * wv.y + v.z * wv.z + v.w * wv.w;
            }
        }
    }

#pragma unroll
    for (int e = 0; e < E_EXP; e++) {
#pragma unroll
        for (int off = 32; off > 0; off >>= 1)
            acc[e] += __shfl_xor(acc[e], off, 64);
    }
    if (lane == 0) {
        int e0 = 0; float l0 = acc[0];
#pragma unroll
        for (int e = 1; e < E_EXP; e++)
            if (acc[e] > l0) { l0 = acc[e]; e0 = e; }
        int e1 = -1; float l1 = -3.4e38f;
#pragma unroll
        for (int e = 0; e < E_EXP; e++)
            if (e != e0 && acc[e] > l1) { l1 = acc[e]; e1 = e; }
        // softmax + top2 + renorm == 1/(1+exp(l1-l0))
        float w0 = 1.f / (1.f + expf(l1 - l0));
        eids[t] = make_int2(e0, e1);
        wts[t] = make_float2(w0, 1.f - w0);
    }
}

// ---------------------------------------------------------------------------
// K3: h-GEMM fused with v build. Block = 32 tokens x 128 er-cols, BK=64,
//     grid 256 (1 block/CU). Epilogue applies SCALING*w masking and writes
//     bf16 straight into xcat cols 4096..4223 (no h buffer round-trip).
// ---------------------------------------------------------------------------
__global__ __launch_bounds__(256) void h_gemm_v(
    const ushort_t* __restrict__ Abf, const int2* __restrict__ eids,
    const float2* __restrict__ wts, ushort_t* __restrict__ xcat) {
    __shared__ __align__(16) ushort_t lA[32 * 64];    // 4 KB
    __shared__ __align__(16) ushort_t lB[128 * 64];   // 16 KB
    int tid = threadIdx.x;
    int lane = tid & 63, wave = tid >> 6;
    int rowBase = blockIdx.x * 32;
    const ushort_t* gA = xcat + (size_t)rowBase * KCAT;

    int rA = tid >> 3;              // 0..31
    int kk = (tid & 7) * 8;         // col within BK=64
    ushort_t* dA = lA + (size_t)wave * 512;   // wave-uniform, 1 KB/wave

    f32x4 acc[2][2];
#pragma unroll
    for (int i = 0; i < 2; i++)
#pragma unroll
        for (int j = 0; j < 2; j++)
            acc[i][j] = (f32x4){0.f, 0.f, 0.f, 0.f};

    int n0 = wave * 32;
    int row16 = lane & 15, q8 = (lane >> 4) * 8;

    for (int kt = 0; kt < D_IN; kt += 64) {
        __syncthreads();
        __builtin_amdgcn_global_load_lds(
            (const __attribute__((address_space(1))) unsigned int*)(gA + (size_t)rA * KCAT + kt + kk),
            (__attribute__((address_space(3))) unsigned int*)dA, 16, 0, 0);
#pragma unroll
        for (int q = 0; q < 4; q++) {
            __builtin_amdgcn_global_load_lds(
                (const __attribute__((address_space(1))) unsigned int*)(
                    Abf + (size_t)((tid >> 3) + 32 * q) * D_IN + kt + kk),
                (__attribute__((address_space(3))) unsigned int*)(
                    lB + (size_t)q * 2048 + (size_t)wave * 512), 16, 0, 0);
        }
        __syncthreads();

        short8 af[2][2], bfrag[2][2];
#pragma unroll
        for (int i = 0; i < 2; i++)
#pragma unroll
            for (int kc = 0; kc < 2; kc++)
                af[i][kc] = *(const short8*)&lA[(i * 16 + row16) * 64 + kc * 32 + q8];
#pragma unroll
        for (int j = 0; j < 2; j++)
#pragma unroll
            for (int kc = 0; kc < 2; kc++)
                bfrag[j][kc] = *(const short8*)&lB[(n0 + j * 16 + row16) * 64 + kc * 32 + q8];
#pragma unroll
        for (int i = 0; i < 2; i++)
#pragma unroll
            for (int j = 0; j < 2; j++) {
                acc[i][j] = __builtin_amdgcn_mfma_f32_16x16x32_bf16(
                    af[i][0], bfrag[j][0], acc[i][j], 0, 0, 0);
                acc[i][j] = __builtin_amdgcn_mfma_f32_16x16x32_bf16(
                    af[i][1], bfrag[j][1], acc[i][j], 0, 0, 0);
            }
    }

    // epilogue: C/D layout col=lane&15, row=(lane>>4)*4+reg; apply coef, write v
#pragma unroll
    for (int i = 0; i < 2; i++) {
        int rbase = rowBase + i * 16 + (lane >> 4) * 4;
#pragma unroll
        for (int reg = 0; reg < 4; reg++) {
            int t = rbase + reg;
            int2 e = eids[t];
            float2 w = wts[t];
#pragma unroll
            for (int j = 0; j < 2; j++) {
                int c = n0 + j * 16 + (lane & 15);
                int ce = c >> 4;
                float coef = (ce == e.x) ? (SCALE_LORA * w.x)
                           : ((ce == e.y) ? (SCALE_LORA * w.y) : 0.f);
                xcat[(size_t)t * KCAT + D_IN + c] = f2bf(coef * acc[i][j][reg]);
            }
        }
    }
}

// ---------------------------------------------------------------------------
// Main GEMM (B^T layout): C[m,n] = sum_k A[m,k]*B[n,k] (+bias[n]).
// 128x128 tile / block (4 waves, each 64x64 via 4x4 of 16x16x32 MFMA), BK=32,
// global_load_lds width-16 staging (m97 structure). Unchanged from round 1.
// ---------------------------------------------------------------------------
__global__ __launch_bounds__(256) void gemm_bt(
    const ushort_t* __restrict__ Am, const ushort_t* __restrict__ Bmat,
    float* __restrict__ C, const float* __restrict__ bias,
    int K, int lda, int ldb, int ldc) {
    __shared__ __align__(16) ushort_t lA[128 * 32];
    __shared__ __align__(16) ushort_t lB[128 * 32];
    int tid = threadIdx.x;
    int lane = tid & 63, wave = tid >> 6;
    const int rowBase = blockIdx.x * 128;
    const int colBase = blockIdx.y * 128;
    const ushort_t* gA = Am + (size_t)rowBase * lda;
    const ushort_t* gB = Bmat + (size_t)colBase * ldb;

    int c0 = tid, c1 = tid + 256;
    int r0 = c0 >> 2, k0 = (c0 & 3) * 8;
    int r1 = c1 >> 2, k1 = (c1 & 3) * 8;
    ushort_t* lA0 = lA + (size_t)wave * 512;
    ushort_t* lA1 = lA + 2048 + (size_t)wave * 512;
    ushort_t* lB0 = lB + (size_t)wave * 512;
    ushort_t* lB1 = lB + 2048 + (size_t)wave * 512;

    f32x4 acc[4][4];
#pragma unroll
    for (int i = 0; i < 4; i++)
#pragma unroll
        for (int j = 0; j < 4; j++)
            acc[i][j] = (f32x4){0.f, 0.f, 0.f, 0.f};

    int m0 = (wave >> 1) * 64, n0 = (wave & 1) * 64;
    int row16 = lane & 15, q8 = (lane >> 4) * 8;

    for (int kt = 0; kt < K; kt += 32) {
        __syncthreads();
        __builtin_amdgcn_global_load_lds(
            (const __attribute__((address_space(1))) unsigned int*)(gA + (size_t)r0 * lda + kt + k0),
            (__attribute__((address_space(3))) unsigned int*)lA0, 16, 0, 0);
        __builtin_amdgcn_global_load_lds(
            (const __attribute__((address_space(1))) unsigned int*)(gA + (size_t)r1 * lda + kt + k1),
            (__attribute__((address_space(3))) unsigned int*)lA1, 16, 0, 0);
        __builtin_amdgcn_global_load_lds(
            (const __attribute__((address_space(1))) unsigned int*)(gB + (size_t)r0 * ldb + kt + k0),
            (__attribute__((address_space(3))) unsigned int*)lB0, 16, 0, 0);
        __builtin_amdgcn_global_load_lds(
            (const __attribute__((address_space(1))) unsigned int*)(gB + (size_t)r1 * ldb + kt + k1),
            (__attribute__((address_space(3))) unsigned int*)lB1, 16, 0, 0);
        __syncthreads();

        short8 af[4], bfr[4];
#pragma unroll
        for (int i = 0; i < 4; i++)
            af[i] = *(const short8*)&lA[(m0 + i * 16 + row16) * 32 + q8];
#pragma unroll
        for (int j = 0; j < 4; j++)
            bfr[j] = *(const short8*)&lB[(n0 + j * 16 + row16) * 32 + q8];
#pragma unroll
        for (int i = 0; i < 4; i++)
#pragma unroll
            for (int j = 0; j < 4; j++)
                acc[i][j] = __builtin_amdgcn_mfma_f32_16x16x32_bf16(
                    af[i], bfr[j], acc[i][j], 0, 0, 0);
    }

#pragma unroll
    for (int i = 0; i < 4; i++) {
        int r = rowBase + m0 + i * 16 + (lane >> 4) * 4;
#pragma unroll
        for (int j = 0; j < 4; j++) {
            int cidx = colBase + n0 + j * 16 + (lane & 15);
            float badd = bias ? bias[cidx] : 0.f;
#pragma unroll
            for (int reg = 0; reg < 4; reg++)
                C[(size_t)(r + reg) * ldc + cidx] = acc[i][j][reg] + badd;
        }
    }
}

// ---------------------------------------------------------------------------
extern "C" void kernel_launch(void* const* d_in, const int* in_sizes, int n_in,
                              void* d_out, int out_size, void* d_ws, size_t ws_size,
                              hipStream_t stream) {
    const float* x    = (const float*)d_in[0];   // [4,2048,4096]
    const float* Wb   = (const float*)d_in[1];   // [4096,4096]
    const float* bias = (const float*)d_in[2];   // [4096]
    const float* Wr   = (const float*)d_in[3];   // [8,4096]
    const float* A    = (const float*)d_in[4];   // [8,16,4096]
    const float* Bm   = (const float*)d_in[5];   // [8,4096,16]
    float* out = (float*)d_out;

    char* p = (char*)d_ws;
    ushort_t* xcat = (ushort_t*)p; p += (size_t)T_TOK * KCAT * 2;   // 69.2 MB
    ushort_t* Wcat = (ushort_t*)p; p += (size_t)D_OUT * KCAT * 2;   // 34.6 MB
    ushort_t* Abf  = (ushort_t*)p; p += (size_t)(E_EXP * R_RANK) * D_IN * 2; // 1 MB
    int2*     eids = (int2*)p;     p += (size_t)T_TOK * sizeof(int2);
    float2*   wts  = (float2*)p;   p += (size_t)T_TOK * sizeof(float2);

    build_weights<<<D_OUT + E_EXP * R_RANK, 256, 0, stream>>>(Wb, Bm, A, Wcat, Abf);
    router_convert<<<T_TOK / 4, 256, 0, stream>>>(x, Wr, xcat, eids, wts);
    // h = xcat[:, :4096] @ Abf^T, scaled+masked, written into xcat cols 4096+
    h_gemm_v<<<T_TOK / 32, 256, 0, stream>>>(Abf, eids, wts, xcat);
    // out[8192,4096] = xcat @ Wcat^T + bias  (K = 4224 includes LoRA fold)
    gemm_bt<<<dim3(T_TOK / 128, D_OUT / 128), 256, 0, stream>>>(
        xcat, Wcat, out, bias, KCAT, KCAT, KCAT, D_OUT);
}

// Round 3
// 684.219 us; speedup vs baseline: 1.1604x; 1.0856x over previous
//
#include <hip/hip_runtime.h>
#include <cmath>

typedef unsigned short ushort_t;
typedef __attribute__((ext_vector_type(8))) short short8;
typedef __attribute__((ext_vector_type(4))) float f32x4;

#define D_IN   4096
#define D_OUT  4096
#define T_TOK  8192
#define E_EXP  8
#define R_RANK 16
#define KCAT   4224   // 4096 + E*R
#define SCALE_LORA 2.0f

__device__ __forceinline__ ushort_t f2bf(float f) {
    unsigned int u = __float_as_uint(f);
    u += 0x7fffu + ((u >> 16) & 1u);   // RNE
    return (ushort_t)(u >> 16);
}

// ---------------------------------------------------------------------------
// K1: Wcat[o][0:4096]=bf16(Wb[o]); Wcat[o][4096+e*16+r]=bf16(Bm[e][o][r]);
//     Abf[e*16+r][:] = bf16(A[e][r][:])
// ---------------------------------------------------------------------------
__global__ __launch_bounds__(256) void build_weights(
    const float* __restrict__ Wb, const float* __restrict__ Bm,
    const float* __restrict__ A, ushort_t* __restrict__ Wcat,
    ushort_t* __restrict__ Abf) {
    int b = blockIdx.x;
    int tid = threadIdx.x;
    if (b < D_OUT) {
        const float4* src = (const float4*)(Wb + (size_t)b * D_IN);
        ushort_t* drow = Wcat + (size_t)b * KCAT;
        for (int c4 = tid; c4 < D_IN / 4; c4 += 256) {
            float4 v = src[c4];
            ushort4 o;
            o.x = f2bf(v.x); o.y = f2bf(v.y); o.z = f2bf(v.z); o.w = f2bf(v.w);
            ((ushort4*)drow)[c4] = o;
        }
        if (tid < E_EXP * R_RANK) {
            int e = tid >> 4, r = tid & 15;
            drow[D_IN + tid] = f2bf(Bm[((size_t)e * D_OUT + b) * R_RANK + r]);
        }
    } else {
        int er = b - D_OUT;   // 0..127
        const float4* src = (const float4*)(A + (size_t)er * D_IN);
        ushort_t* drow = Abf + (size_t)er * D_IN;
        for (int c4 = tid; c4 < D_IN / 4; c4 += 256) {
            float4 v = src[c4];
            ushort4 o;
            o.x = f2bf(v.x); o.y = f2bf(v.y); o.z = f2bf(v.z); o.w = f2bf(v.w);
            ((ushort4*)drow)[c4] = o;
        }
    }
}

// ---------------------------------------------------------------------------
// K2: router + x->bf16 convert. Block = 16 tokens (4 waves x 4 tokens each).
//     Wr staged fp32 in LDS in 2 halves (4 experts = 64 KB); each staged half
//     serves 16 tokens (4x the reuse of the 4-token version: staging traffic
//     268->64 MB, LDS read traffic /4). 4 independent x-row loads per iter.
//     Grid 512 = exactly 2 blocks/CU. Router math fully fp32.
// ---------------------------------------------------------------------------
__global__ __launch_bounds__(256) void router_convert(
    const float* __restrict__ x, const float* __restrict__ Wr,
    ushort_t* __restrict__ xcat, int2* __restrict__ eids,
    float2* __restrict__ wts) {
    __shared__ float sWr[4 * D_IN];   // 64 KB: 4 experts fp32
    int tid = threadIdx.x;
    int lane = tid & 63;
    int wave = tid >> 6;
    int tbase = blockIdx.x * 16 + wave * 4;

    float acc[4][E_EXP];
#pragma unroll
    for (int tk = 0; tk < 4; tk++)
#pragma unroll
        for (int e = 0; e < E_EXP; e++) acc[tk][e] = 0.f;

#pragma unroll
    for (int half = 0; half < 2; half++) {
        __syncthreads();
        {   // stage Wr[half*4 .. half*4+3][:] -> LDS (4096 float4s, 16/thread)
            const float4* wsrc = (const float4*)(Wr + (size_t)half * 4 * D_IN);
            float4* wdst = (float4*)sWr;
#pragma unroll
            for (int q = 0; q < 16; q++)
                wdst[tid + q * 256] = wsrc[tid + q * 256];
        }
        __syncthreads();

        for (int c4 = lane; c4 < D_IN / 4; c4 += 64) {
            float4 wv[4];
#pragma unroll
            for (int e4 = 0; e4 < 4; e4++)
                wv[e4] = ((const float4*)(sWr + (size_t)e4 * D_IN))[c4];
#pragma unroll
            for (int tk = 0; tk < 4; tk++) {
                int t = tbase + tk;
                float4 v = ((const float4*)(x + (size_t)t * D_IN))[c4];
                if (half == 0) {
                    ushort4 o;
                    o.x = f2bf(v.x); o.y = f2bf(v.y); o.z = f2bf(v.z); o.w = f2bf(v.w);
                    ((ushort4*)(xcat + (size_t)t * KCAT))[c4] = o;
                }
#pragma unroll
                for (int e4 = 0; e4 < 4; e4++)
                    acc[tk][half * 4 + e4] +=
                        v.x * wv[e4].x + v.y * wv[e4].y + v.z * wv[e4].z + v.w * wv[e4].w;
            }
        }
    }

#pragma unroll
    for (int tk = 0; tk < 4; tk++)
#pragma unroll
        for (int e = 0; e < E_EXP; e++) {
#pragma unroll
            for (int off = 32; off > 0; off >>= 1)
                acc[tk][e] += __shfl_xor(acc[tk][e], off, 64);
        }
    if (lane == 0) {
#pragma unroll
        for (int tk = 0; tk < 4; tk++) {
            int t = tbase + tk;
            int e0 = 0; float l0 = acc[tk][0];
#pragma unroll
            for (int e = 1; e < E_EXP; e++)
                if (acc[tk][e] > l0) { l0 = acc[tk][e]; e0 = e; }
            int e1 = -1; float l1 = -3.4e38f;
#pragma unroll
            for (int e = 0; e < E_EXP; e++)
                if (e != e0 && acc[tk][e] > l1) { l1 = acc[tk][e]; e1 = e; }
            float w0 = 1.f / (1.f + expf(l1 - l0));   // softmax+top2+renorm
            eids[t] = make_int2(e0, e1);
            wts[t] = make_float2(w0, 1.f - w0);
        }
    }
}

// ---------------------------------------------------------------------------
// K3: h-GEMM fused with v build. Block = 32 tokens x 128 er-cols, BK=64,
//     grid 256 (1 block/CU). Epilogue applies SCALING*w masking and writes
//     bf16 straight into xcat cols 4096..4223 (no h buffer round-trip).
// ---------------------------------------------------------------------------
__global__ __launch_bounds__(256) void h_gemm_v(
    const ushort_t* __restrict__ Abf, const int2* __restrict__ eids,
    const float2* __restrict__ wts, ushort_t* __restrict__ xcat) {
    __shared__ __align__(16) ushort_t lA[32 * 64];    // 4 KB
    __shared__ __align__(16) ushort_t lB[128 * 64];   // 16 KB
    int tid = threadIdx.x;
    int lane = tid & 63, wave = tid >> 6;
    int rowBase = blockIdx.x * 32;
    const ushort_t* gA = xcat + (size_t)rowBase * KCAT;

    int rA = tid >> 3;              // 0..31
    int kk = (tid & 7) * 8;         // col within BK=64
    ushort_t* dA = lA + (size_t)wave * 512;   // wave-uniform, 1 KB/wave

    f32x4 acc[2][2];
#pragma unroll
    for (int i = 0; i < 2; i++)
#pragma unroll
        for (int j = 0; j < 2; j++)
            acc[i][j] = (f32x4){0.f, 0.f, 0.f, 0.f};

    int n0 = wave * 32;
    int row16 = lane & 15, q8 = (lane >> 4) * 8;

    for (int kt = 0; kt < D_IN; kt += 64) {
        __syncthreads();
        __builtin_amdgcn_global_load_lds(
            (const __attribute__((address_space(1))) unsigned int*)(gA + (size_t)rA * KCAT + kt + kk),
            (__attribute__((address_space(3))) unsigned int*)dA, 16, 0, 0);
#pragma unroll
        for (int q = 0; q < 4; q++) {
            __builtin_amdgcn_global_load_lds(
                (const __attribute__((address_space(1))) unsigned int*)(
                    Abf + (size_t)((tid >> 3) + 32 * q) * D_IN + kt + kk),
                (__attribute__((address_space(3))) unsigned int*)(
                    lB + (size_t)q * 2048 + (size_t)wave * 512), 16, 0, 0);
        }
        __syncthreads();

        short8 af[2][2], bfrag[2][2];
#pragma unroll
        for (int i = 0; i < 2; i++)
#pragma unroll
            for (int kc = 0; kc < 2; kc++)
                af[i][kc] = *(const short8*)&lA[(i * 16 + row16) * 64 + kc * 32 + q8];
#pragma unroll
        for (int j = 0; j < 2; j++)
#pragma unroll
            for (int kc = 0; kc < 2; kc++)
                bfrag[j][kc] = *(const short8*)&lB[(n0 + j * 16 + row16) * 64 + kc * 32 + q8];
#pragma unroll
        for (int i = 0; i < 2; i++)
#pragma unroll
            for (int j = 0; j < 2; j++) {
                acc[i][j] = __builtin_amdgcn_mfma_f32_16x16x32_bf16(
                    af[i][0], bfrag[j][0], acc[i][j], 0, 0, 0);
                acc[i][j] = __builtin_amdgcn_mfma_f32_16x16x32_bf16(
                    af[i][1], bfrag[j][1], acc[i][j], 0, 0, 0);
            }
    }

    // epilogue: C/D layout col=lane&15, row=(lane>>4)*4+reg; apply coef, write v
#pragma unroll
    for (int i = 0; i < 2; i++) {
        int rbase = rowBase + i * 16 + (lane >> 4) * 4;
#pragma unroll
        for (int reg = 0; reg < 4; reg++) {
            int t = rbase + reg;
            int2 e = eids[t];
            float2 w = wts[t];
#pragma unroll
            for (int j = 0; j < 2; j++) {
                int c = n0 + j * 16 + (lane & 15);
                int ce = c >> 4;
                float coef = (ce == e.x) ? (SCALE_LORA * w.x)
                           : ((ce == e.y) ? (SCALE_LORA * w.y) : 0.f);
                xcat[(size_t)t * KCAT + D_IN + c] = f2bf(coef * acc[i][j][reg]);
            }
        }
    }
}

// ---------------------------------------------------------------------------
// Main GEMM (B^T layout): C[m,n] = sum_k A[m,k]*B[n,k] (+bias[n]).
// 128x128 tile / block, BK=32, global_load_lds width-16 (m97 structure).
// 1-D grid + grouped swizzle (GROUP_M=8, m-fastest): blocks ≡k (mod 8) land
// on XCD k and share one A-row-tile (1.08 MB, L2-resident) across all 32
// n-tiles -> cuts HBM over-fetch (252 MB measured vs 104 MB working set).
// ---------------------------------------------------------------------------
#define GRID_M (T_TOK / 128)    // 64
#define GRID_N (D_OUT / 128)    // 32

__global__ __launch_bounds__(256) void gemm_bt_main(
    const ushort_t* __restrict__ Am, const ushort_t* __restrict__ Bmat,
    float* __restrict__ C, const float* __restrict__ bias) {
    __shared__ __align__(16) ushort_t lA[128 * 32];
    __shared__ __align__(16) ushort_t lB[128 * 32];
    const int K = KCAT, lda = KCAT, ldb = KCAT, ldc = D_OUT;
    int tid = threadIdx.x;
    int lane = tid & 63, wave = tid >> 6;

    // grouped swizzle: band of 8 m-tiles x 32 n-tiles, m fastest within band
    int bid = blockIdx.x;
    int band = bid >> 8;            // / (8*GRID_N)
    int idx = bid & 255;
    const int rowBase = ((band << 3) + (idx & 7)) * 128;
    const int colBase = (idx >> 3) * 128;

    const ushort_t* gA = Am + (size_t)rowBase * lda;
    const ushort_t* gB = Bmat + (size_t)colBase * ldb;

    int c0 = tid, c1 = tid + 256;
    int r0 = c0 >> 2, k0 = (c0 & 3) * 8;
    int r1 = c1 >> 2, k1 = (c1 & 3) * 8;
    ushort_t* lA0 = lA + (size_t)wave * 512;
    ushort_t* lA1 = lA + 2048 + (size_t)wave * 512;
    ushort_t* lB0 = lB + (size_t)wave * 512;
    ushort_t* lB1 = lB + 2048 + (size_t)wave * 512;

    f32x4 acc[4][4];
#pragma unroll
    for (int i = 0; i < 4; i++)
#pragma unroll
        for (int j = 0; j < 4; j++)
            acc[i][j] = (f32x4){0.f, 0.f, 0.f, 0.f};

    int m0 = (wave >> 1) * 64, n0 = (wave & 1) * 64;
    int row16 = lane & 15, q8 = (lane >> 4) * 8;

    for (int kt = 0; kt < K; kt += 32) {
        __syncthreads();
        __builtin_amdgcn_global_load_lds(
            (const __attribute__((address_space(1))) unsigned int*)(gA + (size_t)r0 * lda + kt + k0),
            (__attribute__((address_space(3))) unsigned int*)lA0, 16, 0, 0);
        __builtin_amdgcn_global_load_lds(
            (const __attribute__((address_space(1))) unsigned int*)(gA + (size_t)r1 * lda + kt + k1),
            (__attribute__((address_space(3))) unsigned int*)lA1, 16, 0, 0);
        __builtin_amdgcn_global_load_lds(
            (const __attribute__((address_space(1))) unsigned int*)(gB + (size_t)r0 * ldb + kt + k0),
            (__attribute__((address_space(3))) unsigned int*)lB0, 16, 0, 0);
        __builtin_amdgcn_global_load_lds(
            (const __attribute__((address_space(1))) unsigned int*)(gB + (size_t)r1 * ldb + kt + k1),
            (__attribute__((address_space(3))) unsigned int*)lB1, 16, 0, 0);
        __syncthreads();

        short8 af[4], bfr[4];
#pragma unroll
        for (int i = 0; i < 4; i++)
            af[i] = *(const short8*)&lA[(m0 + i * 16 + row16) * 32 + q8];
#pragma unroll
        for (int j = 0; j < 4; j++)
            bfr[j] = *(const short8*)&lB[(n0 + j * 16 + row16) * 32 + q8];
#pragma unroll
        for (int i = 0; i < 4; i++)
#pragma unroll
            for (int j = 0; j < 4; j++)
                acc[i][j] = __builtin_amdgcn_mfma_f32_16x16x32_bf16(
                    af[i], bfr[j], acc[i][j], 0, 0, 0);
    }

#pragma unroll
    for (int i = 0; i < 4; i++) {
        int r = rowBase + m0 + i * 16 + (lane >> 4) * 4;
#pragma unroll
        for (int j = 0; j < 4; j++) {
            int cidx = colBase + n0 + j * 16 + (lane & 15);
            float badd = bias[cidx];
#pragma unroll
            for (int reg = 0; reg < 4; reg++)
                C[(size_t)(r + reg) * ldc + cidx] = acc[i][j][reg] + badd;
        }
    }
}

// ---------------------------------------------------------------------------
extern "C" void kernel_launch(void* const* d_in, const int* in_sizes, int n_in,
                              void* d_out, int out_size, void* d_ws, size_t ws_size,
                              hipStream_t stream) {
    const float* x    = (const float*)d_in[0];   // [4,2048,4096]
    const float* Wb   = (const float*)d_in[1];   // [4096,4096]
    const float* bias = (const float*)d_in[2];   // [4096]
    const float* Wr   = (const float*)d_in[3];   // [8,4096]
    const float* A    = (const float*)d_in[4];   // [8,16,4096]
    const float* Bm   = (const float*)d_in[5];   // [8,4096,16]
    float* out = (float*)d_out;

    char* p = (char*)d_ws;
    ushort_t* xcat = (ushort_t*)p; p += (size_t)T_TOK * KCAT * 2;   // 69.2 MB
    ushort_t* Wcat = (ushort_t*)p; p += (size_t)D_OUT * KCAT * 2;   // 34.6 MB
    ushort_t* Abf  = (ushort_t*)p; p += (size_t)(E_EXP * R_RANK) * D_IN * 2; // 1 MB
    int2*     eids = (int2*)p;     p += (size_t)T_TOK * sizeof(int2);
    float2*   wts  = (float2*)p;   p += (size_t)T_TOK * sizeof(float2);

    build_weights<<<D_OUT + E_EXP * R_RANK, 256, 0, stream>>>(Wb, Bm, A, Wcat, Abf);
    router_convert<<<T_TOK / 16, 256, 0, stream>>>(x, Wr, xcat, eids, wts);
    // h = xcat[:, :4096] @ Abf^T, scaled+masked, written into xcat cols 4096+
    h_gemm_v<<<T_TOK / 32, 256, 0, stream>>>(Abf, eids, wts, xcat);
    // out[8192,4096] = xcat @ Wcat^T + bias  (K = 4224 includes LoRA fold)
    gemm_bt_main<<<GRID_M * GRID_N, 256, 0, stream>>>(xcat, Wcat, out, bias);
}